// Round 4
// baseline (2600.072 us; speedup 1.0000x reference)
//
#include <hip/hip_runtime.h>
#include <stdint.h>

#define N_NODES  100000
#define N_EDGES  1600000
#define E_TOT    1700000   // + self loops
#define F_DIM    192
#define IN_DIM   256
#define NGRAPH   64
#define NCLS     10
#define N_WAVES_ATTN 300000          // 100000 dst * 3 heads
#define NODE_ELEMS   19200000LL      // N_NODES * F_DIM

// output element offsets (dtype-independent)
#define LOGITS_OFF 0LL
#define PRE_OFF    640LL
#define PP_OFF     19200640LL
#define FC_OFF     19212928LL

__device__ __forceinline__ float bf2f(unsigned short u) {
  union { unsigned int i; float f; } c; c.i = ((unsigned int)u) << 16; return c.f;
}
__device__ __forceinline__ unsigned short f2bf(float f) {
  union { float f; unsigned int i; } c; c.f = f;
  unsigned int r = (c.i + 0x7FFFu + ((c.i >> 16) & 1u)) >> 16;
  return (unsigned short)r;
}
// dtype-aware float load/store (isbf: 1 = bf16 buffer, 0 = fp32 buffer)
__device__ __forceinline__ float ldf(const void* p, int isbf, long long i) {
  return isbf ? bf2f(((const unsigned short*)p)[i]) : ((const float*)p)[i];
}
__device__ __forceinline__ void stf(void* p, int isbf, long long i, float v) {
  if (isbf) ((unsigned short*)p)[i] = f2bf(v);
  else      ((float*)p)[i] = v;
}
// int32 buffer, or little-endian int64 (read low word)
__device__ __forceinline__ int ld_idx(const int* __restrict__ p, int is64, long long i) {
  return is64 ? p[i << 1] : p[(size_t)i];
}

// restore the template symbol (harness may reference it); launched as a no-op
__global__ void AmazonNet_36704790511894_kernel() {}

// ---------------------------------------------------------------------------
// dtype probe. flags[0]=ei is int64, flags[1]=batch is int64, flags[2]=floats
// are bf16. bf16 test: even-position ushorts of x with exponent 0xFF are
// impossible for finite bf16 data but occur ~1/256 for fp32 mantissa halves.
// ---------------------------------------------------------------------------
__global__ __launch_bounds__(256) void detect_k(const int* __restrict__ ei,
                                                const int* __restrict__ bat,
                                                const unsigned short* __restrict__ x,
                                                int* __restrict__ flags) {
  __shared__ int red[3];
  int t = threadIdx.x;
  if (t < 3) red[t] = 0;
  __syncthreads();
  int o1 = 0, o2 = 0, c3 = 0;
  for (int k = t; k < N_EDGES; k += 256 * 100)   // high words if int64
    o1 |= ei[2 * k + 1];
  for (int k = t; k < 50000; k += 256)           // covers tail (batch sorted)
    o2 |= bat[2 * k + 1];
  for (int k = t; k < 4096; k += 256) {
    unsigned short u = x[2 * k];
    c3 += (((u >> 7) & 0xFF) == 0xFF);
  }
  atomicOr(&red[0], o1);
  atomicOr(&red[1], o2);
  atomicAdd(&red[2], c3);
  __syncthreads();
  if (t == 0) {
    flags[0] = (red[0] == 0);
    flags[1] = (red[1] == 0);
    flags[2] = (red[2] < 4);   // <4 NaN-pattern hits -> genuine bf16
  }
}

// ---------------------------------------------------------------------------
// zero deg|pool_sum|cnt + diagnostic sentinel in logits
// ---------------------------------------------------------------------------
#define ZWORDS (N_NODES + NGRAPH * F_DIM + NGRAPH)   // 112352
__global__ __launch_bounds__(256) void zero_k(int* __restrict__ zbase,
                                              void* __restrict__ dout,
                                              const int* __restrict__ flags) {
  int i = blockIdx.x * 256 + threadIdx.x;
  if (i < ZWORDS) zbase[i] = 0;
  if (i < NGRAPH * NCLS) stf(dout, flags[2], LOGITS_OFF + i, 0.001f);
}

// ---------------------------------------------------------------------------
// VALU fp32 GEMM: block = 32 node-rows x 192 cols. blockIdx < 3125 -> xl
// (stored at FC_OFF), else -> xr (stored at PRE_OFF). x-tile in fp32 LDS,
// thread t owns column t, LDS reads are same-address broadcasts.
// ---------------------------------------------------------------------------
__global__ __launch_bounds__(192) void gemm_valu(const void* __restrict__ x,
                                                 const void* __restrict__ Wl,
                                                 const void* __restrict__ Wr,
                                                 const void* __restrict__ bl,
                                                 const void* __restrict__ br,
                                                 void* __restrict__ dout,
                                                 const int* __restrict__ flags) {
  __shared__ float xs[32][256];
  int fbf = flags[2];
  int t = threadIdx.x;
  int wsel = (blockIdx.x >= 3125);
  int m0 = (wsel ? blockIdx.x - 3125 : blockIdx.x) * 32;
  const void* W    = wsel ? Wr : Wl;
  const void* bias = wsel ? br : bl;
  long long obase  = wsel ? PRE_OFF : FC_OFF;

  for (int v = t; v < 32 * 256; v += 192) {
    int row = v >> 8, k = v & 255;
    xs[row][k] = ldf(x, fbf, (long long)(m0 + row) * IN_DIM + k);
  }
  __syncthreads();

  int n = t;  // column 0..191
  float acc[32];
#pragma unroll
  for (int r = 0; r < 32; ++r) acc[r] = 0.f;

#pragma unroll 4
  for (int k = 0; k < IN_DIM; k += 2) {
    float w0 = ldf(W, fbf, (long long)k * F_DIM + n);
    float w1 = ldf(W, fbf, (long long)(k + 1) * F_DIM + n);
#pragma unroll
    for (int r = 0; r < 32; ++r) {
      float2 xv = *(const float2*)&xs[r][k];
      acc[r] = fmaf(xv.x, w0, acc[r]);
      acc[r] = fmaf(xv.y, w1, acc[r]);
    }
  }
  float bv = ldf(bias, fbf, n);
#pragma unroll
  for (int r = 0; r < 32; ++r)
    stf(dout, fbf, obase + (long long)(m0 + r) * F_DIM + n, acc[r] + bv);
}

// ---------------------------------------------------------------------------
// CSR build by destination
// ---------------------------------------------------------------------------
__global__ __launch_bounds__(256) void hist_k(const int* __restrict__ ei,
                                              const int* __restrict__ batch,
                                              const int* __restrict__ flags,
                                              int* __restrict__ deg,
                                              int* __restrict__ cnt) {
  int is64e = flags[0], is64b = flags[1];
  int e = blockIdx.x * 256 + threadIdx.x;
  if (e < E_TOT) {
    int s, d;
    if (e < N_EDGES) {
      s = ld_idx(ei, is64e, e);
      d = ld_idx(ei, is64e, (long long)N_EDGES + e);
    } else s = d = e - N_EDGES;
    if ((unsigned)d < (unsigned)N_NODES && (unsigned)s < (unsigned)N_NODES)
      atomicAdd(&deg[d], 1);
  }
  if (e < N_NODES) {
    int g = ld_idx(batch, is64b, e);
    if ((unsigned)g < (unsigned)NGRAPH) atomicAdd(&cnt[g], 1);
  }
}

__global__ __launch_bounds__(256) void scan_a(const int* __restrict__ deg, int* __restrict__ csum) {
  __shared__ int red[256];
  int b = blockIdx.x, t = threadIdx.x;
  int base = b * 1024 + t * 4;
  int s = 0;
#pragma unroll
  for (int k = 0; k < 4; ++k) { int idx = base + k; if (idx < N_NODES) s += deg[idx]; }
  red[t] = s;
  __syncthreads();
  for (int off = 128; off; off >>= 1) {
    if (t < off) red[t] += red[t + off];
    __syncthreads();
  }
  if (t == 0) csum[b] = red[0];
}

__global__ void scan_b(int* csum, int* row_ptr, int nblk) {
  if (threadIdx.x == 0 && blockIdx.x == 0) {
    int run = 0;
    for (int b = 0; b < nblk; ++b) { int s = csum[b]; csum[b] = run; run += s; }
    row_ptr[N_NODES] = run;
  }
}

__global__ __launch_bounds__(256) void scan_c(const int* __restrict__ deg,
                                              const int* __restrict__ csum,
                                              int* __restrict__ row_ptr,
                                              int* __restrict__ cursor) {
  __shared__ int tsum[256];
  int b = blockIdx.x, t = threadIdx.x;
  int base = b * 1024 + t * 4;
  int v[4];
  int s = 0;
#pragma unroll
  for (int k = 0; k < 4; ++k) {
    int idx = base + k;
    v[k] = (idx < N_NODES) ? deg[idx] : 0;
    s += v[k];
  }
  tsum[t] = s;
  __syncthreads();
  for (int off = 1; off < 256; off <<= 1) {
    int x = (t >= off) ? tsum[t - off] : 0;
    __syncthreads();
    tsum[t] += x;
    __syncthreads();
  }
  int run = csum[b] + tsum[t] - s;
#pragma unroll
  for (int k = 0; k < 4; ++k) {
    int idx = base + k;
    if (idx < N_NODES) { row_ptr[idx] = run; cursor[idx] = run; }
    run += v[k];
  }
}

__global__ __launch_bounds__(256) void fill_k(const int* __restrict__ ei,
                                              const int* __restrict__ flags,
                                              int* __restrict__ cursor,
                                              int* __restrict__ edge_src) {
  int is64e = flags[0];
  int e = blockIdx.x * 256 + threadIdx.x;
  if (e >= E_TOT) return;
  int s, d;
  if (e < N_EDGES) {
    s = ld_idx(ei, is64e, e);
    d = ld_idx(ei, is64e, (long long)N_EDGES + e);
  } else s = d = e - N_EDGES;
  if ((unsigned)d < (unsigned)N_NODES && (unsigned)s < (unsigned)N_NODES) {
    int pos = atomicAdd(&cursor[d], 1);
    edge_src[pos] = s;
  }
}

// ---------------------------------------------------------------------------
// Pass 1: one wave per (dst, head). xl lives at FC_OFF (read-only here),
// xr at PRE_OFF. Online softmax; writes fc (with bias) into PRE_OFF slot —
// that slot is read only by this wave, so no cross-wave hazard.
// ---------------------------------------------------------------------------
__global__ __launch_bounds__(256) void attn1_k(void* __restrict__ dout,
                                               const void* __restrict__ att,
                                               const void* __restrict__ bias,
                                               const int* __restrict__ row_ptr,
                                               const int* __restrict__ edge_src,
                                               const int* __restrict__ flags) {
  int fbf = flags[2];
  int lane = threadIdx.x & 63;
  int gw = blockIdx.x * 4 + (threadIdx.x >> 6);
  if (gw >= N_WAVES_ATTN) return;
  int i = gw / 3;
  int h = gw - i * 3;
  int c = h * 64 + lane;

  float xr_t = ldf(dout, fbf, PRE_OFF + (long long)i * F_DIM + c);
  float at   = ldf(att, fbf, c);
  int start = row_ptr[i];
  int end   = row_ptr[i + 1];

  float m = -1e30f, s = 0.f, o = 0.f;
  float xlv = 0.f;
  if (start < end)
    xlv = ldf(dout, fbf, FC_OFF + (long long)edge_src[start] * F_DIM + c);
  for (int e = start; e < end; ++e) {
    float xln = 0.f;
    if (e + 1 < end)
      xln = ldf(dout, fbf, FC_OFF + (long long)edge_src[e + 1] * F_DIM + c);
    float tt = xlv + xr_t;
    tt = tt > 0.f ? tt : 0.2f * tt;              // GATv2 leaky_relu, slope 0.2
    float p = tt * at;
#pragma unroll
    for (int d = 32; d; d >>= 1) p += __shfl_xor(p, d);  // head logit
    float mn = fmaxf(m, p);
    float cf = __expf(m - mn);
    float w  = __expf(p - mn);
    s = s * cf + w;
    o = o * cf + w * xlv;
    m = mn;
    xlv = xln;
  }
  float val = (s > 0.f ? o / s : 0.f) + ldf(bias, fbf, c);
  stf(dout, fbf, PRE_OFF + (long long)i * F_DIM + c, val);
}

// ---------------------------------------------------------------------------
// Pass 2: fc (at PRE_OFF) -> out_fc; leaky_relu(fc) -> out_pre; pool atomics.
// ---------------------------------------------------------------------------
__global__ __launch_bounds__(256) void post_k(void* __restrict__ dout,
                                              const int* __restrict__ batch,
                                              const int* __restrict__ flags,
                                              float* __restrict__ pool_sum) {
  int fbf = flags[2], is64b = flags[1];
  long long idx = (long long)blockIdx.x * 256 + threadIdx.x;
  if (idx >= NODE_ELEMS) return;
  int i = (int)(idx / F_DIM);
  int c = (int)(idx - (long long)i * F_DIM);
  float fc = ldf(dout, fbf, PRE_OFF + idx);
  stf(dout, fbf, FC_OFF + idx, fc);
  float pre = fc > 0.f ? fc : 0.01f * fc;        // F.leaky_relu default slope
  stf(dout, fbf, PRE_OFF + idx, pre);
  int g = ld_idx(batch, is64b, i);
  if ((unsigned)g < (unsigned)NGRAPH)
    atomicAdd(&pool_sum[g * F_DIM + c], pre);
}

// ---------------------------------------------------------------------------
__global__ __launch_bounds__(192) void final_k(const float* __restrict__ pool_sum,
                                               const int* __restrict__ cnt,
                                               const void* __restrict__ Wc,
                                               const void* __restrict__ bc,
                                               void* __restrict__ dout,
                                               const int* __restrict__ flags) {
  __shared__ float sp[F_DIM];
  int fbf = flags[2];
  int g = blockIdx.x, t = threadIdx.x;
  int cn = cnt[g]; if (cn < 1) cn = 1;
  float pv = pool_sum[g * F_DIM + t] / (float)cn;
  stf(dout, fbf, PP_OFF + (long long)g * F_DIM + t, pv);
  sp[t] = pv;
  __syncthreads();
  if (t < NCLS) {
    float a = ldf(bc, fbf, t);
#pragma unroll 4
    for (int cc = 0; cc < F_DIM; ++cc) a += sp[cc] * ldf(Wc, fbf, cc * NCLS + t);
    stf(dout, fbf, LOGITS_OFF + (long long)g * NCLS + t, a);
  }
}

// ---------------------------------------------------------------------------
extern "C" void kernel_launch(void* const* d_in, const int* in_sizes, int n_in,
                              void* d_out, int out_size, void* d_ws, size_t ws_size,
                              hipStream_t stream) {
  const void* x    = d_in[0];
  const int*  ei   = (const int*)d_in[1];
  const int*  bat  = (const int*)d_in[2];
  const void* Wl   = d_in[3];
  const void* bl   = d_in[4];
  const void* Wr   = d_in[5];
  const void* br   = d_in[6];
  const void* att  = d_in[7];
  const void* bias = d_in[8];
  const void* Wc   = d_in[9];
  const void* bc   = d_in[10];

  // workspace carve — total ~8.1 MB
  char* p = (char*)d_ws;
  auto carve = [&](size_t bytes) { char* r = p; p += (bytes + 511) & ~(size_t)511; return r; };
  int*   flags    = (int*)carve(3 * 4);
  int*   zbase    = (int*)carve((size_t)ZWORDS * 4);   // deg | pool_sum | cnt
  int*   deg      = zbase;
  float* pool_sum = (float*)(zbase + N_NODES);
  int*   cnt      = zbase + N_NODES + NGRAPH * F_DIM;
  int* row_ptr  = (int*)carve((size_t)(N_NODES + 1) * 4);
  int* cursor   = (int*)carve((size_t)N_NODES * 4);
  int* csum     = (int*)carve(128 * 4);
  int* edge_src = (int*)carve((size_t)E_TOT * 4);      // 6.8 MB

  AmazonNet_36704790511894_kernel<<<1, 64, 0, stream>>>();   // template symbol no-op
  detect_k<<<1, 256, 0, stream>>>(ei, bat, (const unsigned short*)x, flags);
  zero_k<<<(ZWORDS + 255) / 256, 256, 0, stream>>>(zbase, d_out, flags);

  // linear transforms: xl -> FC_OFF region, xr -> PRE_OFF region (both d_out)
  gemm_valu<<<6250, 192, 0, stream>>>(x, Wl, Wr, bl, br, d_out, flags);

  // CSR by destination
  int eblk = (E_TOT + 255) / 256;
  hist_k<<<eblk, 256, 0, stream>>>(ei, bat, flags, deg, cnt);
  int nchunk = (N_NODES + 1023) / 1024;   // 98
  scan_a<<<nchunk, 256, 0, stream>>>(deg, csum);
  scan_b<<<1, 64, 0, stream>>>(csum, row_ptr, nchunk);
  scan_c<<<nchunk, 256, 0, stream>>>(deg, csum, row_ptr, cursor);
  fill_k<<<eblk, 256, 0, stream>>>(ei, flags, cursor, edge_src);

  // attention (pass1: fc -> PRE_OFF), then finalize outputs + pooling
  attn1_k<<<(N_WAVES_ATTN + 3) / 4, 256, 0, stream>>>(d_out, att, bias, row_ptr,
                                                      edge_src, flags);
  post_k<<<(int)((NODE_ELEMS + 255) / 256), 256, 0, stream>>>(d_out, bat, flags, pool_sum);
  final_k<<<NGRAPH, F_DIM, 0, stream>>>(pool_sum, cnt, Wc, bc, d_out, flags);
}